// Round 4
// baseline (498.713 us; speedup 1.0000x reference)
//
#include <hip/hip_runtime.h>
#include <math.h>

// ---------------------------------------------------------------------------
// InfoNCE on MI355X — v7.
// T1[i,j] = tail(relu(hx[j]+hy[i]+b1)) = fused GEMM M=262144, N=512, K=512,
// A formed on the fly; 2 MFMA products (A bf16, B hi/lo split), 32x32x16.
// v7 vs v6: ILP-not-TLP. v6 (16 waves, wave=128x32) oversubscribed the
// CU-shared LDS port (64 b128 reads per half-step = 74% port util -> queue
// delays at each lgkmcnt) and had 0 spare arch VGPRs to prefetch into.
// v7: 512 thr / 8 waves (2/SIMD, HK-style), wave tile 128x64 (acc 128 regs,
// budget 256): one A-read now feeds 16... 4 MFMA (4x v6), LDS port at 37%,
// and BOTH A and B are register-double-buffered a full half-step ahead.
// Barrier-free K-loop + full-K A tile in 133 KB dynamic LDS retained.
// rowlse+final merged into one reduce kernel (one fewer launch gap).
// ---------------------------------------------------------------------------

typedef __bf16 bf16x8 __attribute__((ext_vector_type(8)));
typedef float  f32x16 __attribute__((ext_vector_type(16)));

#define H    512
#define NPTS 512
#define XD   128
#define SPA  520   // A-tile LDS row stride (elems): 1040 B, 2-way-free banks
#define PLS  12    // epilogue partial-scratch row stride (f32), float4-aligned

// ---------------- prep: hx, hy(+b1); W2 -> fragment-major bf16 hi/lo ------
__global__ __launch_bounds__(256) void prep_kernel(
    const float* __restrict__ x, const float* __restrict__ y,
    const float* __restrict__ W1x, const float* __restrict__ W1y,
    const float* __restrict__ b1, const float* __restrict__ W2,
    float* __restrict__ hx, float* __restrict__ hy,
    __bf16* __restrict__ w2h, __bf16* __restrict__ w2l) {
  __shared__ float xr[XD];
  const int b = blockIdx.x;
  const int t = threadIdx.x;
  if (b < 2 * NPTS) {
    const bool isY = (b >= NPTS);
    const int row = isY ? b - NPTS : b;
    const float* src = isY ? y : x;      // [NPTS][XD]
    const float* W   = isY ? W1y : W1x;  // [XD][H]
    if (t < XD) xr[t] = src[row * XD + t];
    __syncthreads();
    for (int c = t; c < H; c += 256) {
      float s = 0.f;
#pragma unroll
      for (int k = 0; k < XD; ++k) s = fmaf(xr[k], W[k * H + c], s);
      if (isY) hy[row * H + c] = s + b1[c];   // fold b1 into hy
      else     hx[row * H + c] = s;
    }
  } else {
    // W2[k][n] -> 32x32x16-fragment-major:
    // idx = ((n>>5)*32 + (k>>4))*512 + (n&31)*16 + (k&15)
    // one 1KB frag = 32 cols x 16 k; lane l holds col = l&31, k = (l>>5)*8+e.
    const int n = b - 2 * NPTS;
    for (int k = t; k < H; k += 256) {
      float v = W2[k * H + n];
      __bf16 hi = (__bf16)v;
      float lo = v - (float)hi;
      const int idx = (((n >> 5) * 32) + (k >> 4)) * 512 + (n & 31) * 16 + (k & 15);
      w2h[idx] = hi;
      w2l[idx] = (__bf16)lo;
    }
  }
}

// ---------------- pair GEMM + fused tail -> T1 (post-softplus) ------------
// grid 2048 = 32 i-groups x 64 j-groups; M-tile = 128 pairs (16 i x 8 j).
// 512 threads = 8 waves; wave w = n-group: all 128 rows x cols [w*64,w*64+64)
// (4 m-tiles x 2 n-tiles; acc[4][2] f32x16). K in 32 half-steps of 16;
// A and B double-buffered in registers; no barrier inside the K-loop.
__global__ __launch_bounds__(512, 2) void pair_kernel(
    const float* __restrict__ hx, const float* __restrict__ hy,
    const __bf16* __restrict__ w2h, const __bf16* __restrict__ w2l,
    const float* __restrict__ b2, const float* __restrict__ W3,
    const float* __restrict__ b3, float* __restrict__ T1) {
  extern __shared__ __align__(16) __bf16 Ah[];   // [128][SPA] = 133120 B

  const int t    = threadIdx.x;
  const int i0   = (blockIdx.x >> 6) * 16;
  const int j0   = (blockIdx.x & 63) * 8;
  const int wave = t >> 6;        // n-group 0..7 (cols wave*64..wave*64+63)
  const int lane = t & 63;
  const int r31  = lane & 31;
  const int half = lane >> 5;

  // B frag addressing: groups g = wave*2 + nt; base(nt,hs) = (g*32+hs)*512+boff
  const int boff = r31 * 16 + half * 8;
  const __bf16* w2hW = w2h + wave * 32768 + boff;
  const __bf16* w2lW = w2l + wave * 32768 + boff;

  // issue B loads for half-step 0 before staging (land during it)
  bf16x8 Bh[2][2], Bl[2][2];
  Bh[0][0] = *(const bf16x8*)(w2hW);
  Bh[0][1] = *(const bf16x8*)(w2hW + 16384);
  Bl[0][0] = *(const bf16x8*)(w2lW);
  Bl[0][1] = *(const bf16x8*)(w2lW + 16384);

  // ---- upfront staging of the whole 128 x 512 A tile -----------------
  // 4 threads per row, 16 segs (of 8 elems) per thread.
  {
    const int sm = t >> 2;        // pair row 0..127  (ti = sm>>3, tj = sm&7)
    const int sl = t & 3;
    const float* hxp = hx + (j0 + (sm & 7)) * H;
    const float* hyp = hy + (i0 + (sm >> 3)) * H;
    __bf16* arow = Ah + sm * SPA;
#pragma unroll
    for (int c = 0; c < 16; ++c) {
      const int k = (sl + c * 4) * 8;
      float4 x0 = *(const float4*)(hxp + k);
      float4 x1 = *(const float4*)(hxp + k + 4);
      float4 y0 = *(const float4*)(hyp + k);
      float4 y1 = *(const float4*)(hyp + k + 4);
      float a[8] = {x0.x + y0.x, x0.y + y0.y, x0.z + y0.z, x0.w + y0.w,
                    x1.x + y1.x, x1.y + y1.y, x1.z + y1.z, x1.w + y1.w};
      bf16x8 hv;
#pragma unroll
      for (int e = 0; e < 8; ++e) {
        float v = a[e] > 0.f ? a[e] : 0.f;   // first relu
        hv[e] = (__bf16)v;
      }
      *(bf16x8*)(&arow[k]) = hv;
    }
  }

  // A-frag LDS offsets (elems): row = mt*32 + r31, k-base = half*8 (+hs*16)
  int aoff[4];
#pragma unroll
  for (int mt = 0; mt < 4; ++mt) aoff[mt] = (mt * 32 + r31) * SPA + half * 8;

  f32x16 acc[4][2] = {};

  __syncthreads();   // staging complete; only barrier before epilogue

  // prologue A frags for half-step 0 (after barrier!)
  bf16x8 Ab[2][4];
#pragma unroll
  for (int mt = 0; mt < 4; ++mt) Ab[0][mt] = *(const bf16x8*)(Ah + aoff[mt]);

  // ---- barrier-free K-loop: 32 half-steps of K=16 --------------------
#pragma unroll
  for (int hs = 0; hs < 32; ++hs) {
    const int cur = hs & 1;
    if (hs < 31) {   // prefetch B and A for next half-step (full hs to land)
      const int bo = (hs + 1) * 512;
      Bh[cur ^ 1][0] = *(const bf16x8*)(w2hW + bo);
      Bh[cur ^ 1][1] = *(const bf16x8*)(w2hW + 16384 + bo);
      Bl[cur ^ 1][0] = *(const bf16x8*)(w2lW + bo);
      Bl[cur ^ 1][1] = *(const bf16x8*)(w2lW + 16384 + bo);
#pragma unroll
      for (int mt = 0; mt < 4; ++mt)
        Ab[cur ^ 1][mt] = *(const bf16x8*)(Ah + aoff[mt] + (hs + 1) * 16);
    }
    // 16 MFMA: 8 independent Bh products, then 8 Bl (dep distance 8)
    __builtin_amdgcn_s_setprio(1);
#pragma unroll
    for (int mt = 0; mt < 4; ++mt) {
      acc[mt][0] = __builtin_amdgcn_mfma_f32_32x32x16_bf16(Ab[cur][mt], Bh[cur][0], acc[mt][0], 0, 0, 0);
      acc[mt][1] = __builtin_amdgcn_mfma_f32_32x32x16_bf16(Ab[cur][mt], Bh[cur][1], acc[mt][1], 0, 0, 0);
    }
#pragma unroll
    for (int mt = 0; mt < 4; ++mt) {
      acc[mt][0] = __builtin_amdgcn_mfma_f32_32x32x16_bf16(Ab[cur][mt], Bl[cur][0], acc[mt][0], 0, 0, 0);
      acc[mt][1] = __builtin_amdgcn_mfma_f32_32x32x16_bf16(Ab[cur][mt], Bl[cur][1], acc[mt][1], 0, 0, 0);
    }
    __builtin_amdgcn_s_setprio(0);
  }

  __syncthreads();   // all waves done reading Ah -> safe to alias its LDS

  // epilogue: v = relu(h2 + b2); p = v*W3 (2 cols/lane presummed);
  // 5-stage shfl over 32 lanes -> per-(row, n-group) partials in LDS
  // (aliasing the dead A tile), final 128-thread reduce + softplus.
  float* PL = (float*)Ah;            // [128][PLS]
  const float bb0 = b2[wave * 64 + r31];
  const float bb1 = b2[wave * 64 + 32 + r31];
  const float w30 = W3[wave * 64 + r31];
  const float w31 = W3[wave * 64 + 32 + r31];
#pragma unroll
  for (int mt = 0; mt < 4; ++mt) {
#pragma unroll
    for (int r = 0; r < 16; ++r) {
      float v0 = acc[mt][0][r] + bb0;
      float v1 = acc[mt][1][r] + bb1;
      v0 = v0 > 0.f ? v0 : 0.f;            // second relu
      v1 = v1 > 0.f ? v1 : 0.f;
      float p = fmaf(v0, w30, v1 * w31);
      p += __shfl_xor(p, 1);
      p += __shfl_xor(p, 2);
      p += __shfl_xor(p, 4);
      p += __shfl_xor(p, 8);
      p += __shfl_xor(p, 16);
      if (r31 == 0) {
        const int row = mt * 32 + (r & 3) + 8 * (r >> 2) + 4 * half;
        PL[row * PLS + wave] = p;
      }
    }
  }
  __syncthreads();
  if (t < 128) {
    float4 q0 = *(const float4*)(PL + t * PLS);
    float4 q1 = *(const float4*)(PL + t * PLS + 4);
    float s = b3[0] + q0.x + q0.y + q0.z + q0.w + q1.x + q1.y + q1.z + q1.w;
    const float sp = s > 0.f ? s + log1pf(expf(-s)) : log1pf(expf(s));
    const int ti = t >> 3, tj = t & 7;
    T1[(i0 + ti) * NPTS + (j0 + tj)] = sp;   // row = i (hy), col = j (hx)
  }
}

// ---------------- merged reduce: row-lse + diag + final scalar ------------
// one block, 1024 threads = 16 waves; wave w handles rows w*32..w*32+31.
__global__ __launch_bounds__(1024) void reduce_kernel(
    const float* __restrict__ T1, float* __restrict__ out) {
  __shared__ float sL[16], sD[16];
  const int t = threadIdx.x, wave = t >> 6, lane = t & 63;
  float accL = 0.f;
  for (int rr = 0; rr < 32; ++rr) {
    const float* row = T1 + (wave * 32 + rr) * NPTS;
    float se = 0.f;
#pragma unroll
    for (int q = 0; q < 8; ++q) se += expf(row[lane + q * 64]);
#pragma unroll
    for (int off = 1; off < 64; off <<= 1) se += __shfl_xor(se, off);
    if (lane == 0) accL += logf(se);
  }
  float accD = (t < NPTS) ? T1[t * (NPTS + 1)] : 0.f;   // diag == T0
#pragma unroll
  for (int off = 1; off < 64; off <<= 1) accD += __shfl_xor(accD, off);
  if (lane == 0) { sL[wave] = accL; sD[wave] = accD; }
  __syncthreads();
  if (t == 0) {
    float sa = 0.f, sb = 0.f;
#pragma unroll
    for (int i = 0; i < 16; ++i) { sa += sD[i]; sb += sL[i]; }
    out[0] = sa / 512.0f - sb / 512.0f + logf(512.0f);
  }
}

// ---------------------------------------------------------------------------
extern "C" void kernel_launch(void* const* d_in, const int* in_sizes, int n_in,
                              void* d_out, int out_size, void* d_ws, size_t ws_size,
                              hipStream_t stream) {
  const float* x   = (const float*)d_in[0];
  const float* y   = (const float*)d_in[1];
  const float* W1x = (const float*)d_in[2];
  const float* W1y = (const float*)d_in[3];
  const float* b1  = (const float*)d_in[4];
  const float* W2  = (const float*)d_in[5];
  const float* b2  = (const float*)d_in[6];
  const float* W3  = (const float*)d_in[7];
  const float* b3  = (const float*)d_in[8];

  float* ws = (float*)d_ws;
  float* hx = ws;                         // 512*512 f32
  float* hy = ws + 262144;                // 512*512 f32
  float* T1 = ws + 524288;                // 512*512 f32
  __bf16* w2h = (__bf16*)(ws + 786432);   // 512*512 bf16 (fragment-major)
  __bf16* w2l = w2h + 262144;             // 512*512 bf16
  float* out = (float*)d_out;

  // dynamic LDS: 128 rows x SPA(520) x 2B = 133120 B (>64 KB default cap)
  static bool configured = false;
  if (!configured) {
    hipFuncSetAttribute(reinterpret_cast<const void*>(pair_kernel),
                        hipFuncAttributeMaxDynamicSharedMemorySize,
                        128 * SPA * 2);
    configured = true;
  }

  hipLaunchKernelGGL(prep_kernel, dim3(1536), dim3(256), 0, stream,
                     x, y, W1x, W1y, b1, W2, hx, hy, w2h, w2l);
  hipLaunchKernelGGL(pair_kernel, dim3(2048), dim3(512), 128 * SPA * 2, stream,
                     hx, hy, w2h, w2l, b2, W3, b3, T1);
  hipLaunchKernelGGL(reduce_kernel, dim3(1), dim3(1024), 0, stream, T1, out);
}

// Round 5
// 429.481 us; speedup vs baseline: 1.1612x; 1.1612x over previous
//
#include <hip/hip_runtime.h>
#include <math.h>

// ---------------------------------------------------------------------------
// InfoNCE on MI355X — v8.
// T1[i,j] = tail(relu(hx[j]+hy[i]+b1)) = fused GEMM M=262144, N=512, K=512,
// A formed on the fly; 2 MFMA products (A bf16, B hi/lo split), 32x32x16.
// v8 vs v7: PHASE DIVERSITY via 2 blocks/CU. v4-v7 post-mortems: one
// 32x32x16 MFMA = 32 cyc/SIMD (2495 TF = 1015 FLOP/cyc/SIMD), and every
// variant was limited by exposed load latency because the 133 KB full-K
// A-tile forced 1 block/CU -> all waves same-block, phase-coupled, 1-deep
// prefetch drained every iteration. v8: M-tile 64 -> A-tile 66.5 KB -> 2
// independent blocks/CU; 8 waves/block, wave tile 64x64 (acc[2][2]=64 regs,
// ~60 arch), launch_bounds(512,4) -> 4 waves/SIMD from 2 barrier-independent
// blocks. B L2 traffic doubles (4 GB, ~26 TB/s < 34.5 ceiling) - accepted.
// Barrier-free K-loop, v6's conflict-free staging/read patterns, v5's split
// reduce kernels restored (v7's 1-block merged reduce cost ~30 us).
// ---------------------------------------------------------------------------

typedef __bf16 bf16x8 __attribute__((ext_vector_type(8)));
typedef float  f32x16 __attribute__((ext_vector_type(16)));

#define H    512
#define NPTS 512
#define XD   128
#define SPA  520   // A-tile LDS row stride (elems): 1040 B
#define PLS  12    // epilogue partial-scratch row stride (f32)

// ---------------- prep: hx, hy(+b1); W2 -> fragment-major bf16 hi/lo ------
__global__ __launch_bounds__(256) void prep_kernel(
    const float* __restrict__ x, const float* __restrict__ y,
    const float* __restrict__ W1x, const float* __restrict__ W1y,
    const float* __restrict__ b1, const float* __restrict__ W2,
    float* __restrict__ hx, float* __restrict__ hy,
    __bf16* __restrict__ w2h, __bf16* __restrict__ w2l) {
  __shared__ float xr[XD];
  const int b = blockIdx.x;
  const int t = threadIdx.x;
  if (b < 2 * NPTS) {
    const bool isY = (b >= NPTS);
    const int row = isY ? b - NPTS : b;
    const float* src = isY ? y : x;      // [NPTS][XD]
    const float* W   = isY ? W1y : W1x;  // [XD][H]
    if (t < XD) xr[t] = src[row * XD + t];
    __syncthreads();
    for (int c = t; c < H; c += 256) {
      float s = 0.f;
#pragma unroll
      for (int k = 0; k < XD; ++k) s = fmaf(xr[k], W[k * H + c], s);
      if (isY) hy[row * H + c] = s + b1[c];   // fold b1 into hy
      else     hx[row * H + c] = s;
    }
  } else {
    // W2[k][n] -> 32x32x16-fragment-major:
    // idx = ((n>>5)*32 + (k>>4))*512 + (n&31)*16 + (k&15)
    // one 1KB frag = 32 cols x 16 k; lane l holds col = l&31, k = (l>>5)*8+e.
    const int n = b - 2 * NPTS;
    for (int k = t; k < H; k += 256) {
      float v = W2[k * H + n];
      __bf16 hi = (__bf16)v;
      float lo = v - (float)hi;
      const int idx = (((n >> 5) * 32) + (k >> 4)) * 512 + (n & 31) * 16 + (k & 15);
      w2h[idx] = hi;
      w2l[idx] = (__bf16)lo;
    }
  }
}

// ---------------- pair GEMM + fused tail -> T1 (post-softplus) ------------
// grid 4096 = 64 i-groups x 64 j-groups; M-tile = 64 pairs (8 i x 8 j).
// 512 threads = 8 waves; wave w = n-group: all 64 rows x cols [w*64,w*64+64)
// (2 m-tiles x 2 n-tiles; acc[2][2] f32x16 = 64 regs). K in 32 half-steps
// of 16; A and B register-double-buffered; no barrier inside the K-loop.
// 66.5 KB LDS -> 2 independent blocks/CU -> 4 phase-diverse waves/SIMD.
__global__ __launch_bounds__(512, 4) void pair_kernel(
    const float* __restrict__ hx, const float* __restrict__ hy,
    const __bf16* __restrict__ w2h, const __bf16* __restrict__ w2l,
    const float* __restrict__ b2, const float* __restrict__ W3,
    const float* __restrict__ b3, float* __restrict__ T1) {
  extern __shared__ __align__(16) __bf16 Ah[];   // [64][SPA] = 66560 B

  const int t    = threadIdx.x;
  const int i0   = (blockIdx.x >> 6) * 8;
  const int j0   = (blockIdx.x & 63) * 8;
  const int wave = t >> 6;        // n-group 0..7 (cols wave*64..wave*64+63)
  const int lane = t & 63;
  const int r31  = lane & 31;
  const int half = lane >> 5;

  // B frag addressing: groups g = wave*2 + nt; base(nt,hs) = (g*32+hs)*512+boff
  const int boff = r31 * 16 + half * 8;
  const __bf16* w2hW = w2h + wave * 32768 + boff;
  const __bf16* w2lW = w2l + wave * 32768 + boff;

  // issue B loads for half-step 0 before staging (land during it)
  bf16x8 Bh[2][2], Bl[2][2];
  Bh[0][0] = *(const bf16x8*)(w2hW);
  Bh[0][1] = *(const bf16x8*)(w2hW + 16384);
  Bl[0][0] = *(const bf16x8*)(w2lW);
  Bl[0][1] = *(const bf16x8*)(w2lW + 16384);

  // ---- upfront staging of the whole 64 x 512 A tile (v6 pattern) -----
  // 8 threads per row, 8 segs (of 8 elems) per thread.
  {
    const int sm = t >> 3;        // pair row 0..63  (ti = sm>>3, tj = sm&7)
    const int sl = t & 7;
    const float* hxp = hx + (j0 + (sm & 7)) * H;
    const float* hyp = hy + (i0 + (sm >> 3)) * H;
    __bf16* arow = Ah + sm * SPA;
#pragma unroll
    for (int c = 0; c < 8; ++c) {
      const int k = sl * 8 + c * 64;
      float4 x0 = *(const float4*)(hxp + k);
      float4 x1 = *(const float4*)(hxp + k + 4);
      float4 y0 = *(const float4*)(hyp + k);
      float4 y1 = *(const float4*)(hyp + k + 4);
      float a[8] = {x0.x + y0.x, x0.y + y0.y, x0.z + y0.z, x0.w + y0.w,
                    x1.x + y1.x, x1.y + y1.y, x1.z + y1.z, x1.w + y1.w};
      bf16x8 hv;
#pragma unroll
      for (int e = 0; e < 8; ++e) {
        float v = a[e] > 0.f ? a[e] : 0.f;   // first relu
        hv[e] = (__bf16)v;
      }
      *(bf16x8*)(&arow[k]) = hv;
    }
  }

  // A-frag LDS offsets (elems): row = mt*32 + r31, k-base = half*8 (+hs*16)
  const int aoff0 = r31 * SPA + half * 8;

  f32x16 acc[2][2] = {};

  __syncthreads();   // staging complete; only barrier before epilogue

  // prologue A frags for half-step 0 (after barrier!)
  bf16x8 Ab[2][2];
  Ab[0][0] = *(const bf16x8*)(Ah + aoff0);
  Ab[0][1] = *(const bf16x8*)(Ah + aoff0 + 32 * SPA);

  // ---- barrier-free K-loop: 32 half-steps of K=16 --------------------
#pragma unroll
  for (int hs = 0; hs < 32; ++hs) {
    const int cur = hs & 1;
    if (hs < 31) {   // prefetch B and A for next half-step
      const int bo = (hs + 1) * 512;
      Bh[cur ^ 1][0] = *(const bf16x8*)(w2hW + bo);
      Bh[cur ^ 1][1] = *(const bf16x8*)(w2hW + 16384 + bo);
      Bl[cur ^ 1][0] = *(const bf16x8*)(w2lW + bo);
      Bl[cur ^ 1][1] = *(const bf16x8*)(w2lW + 16384 + bo);
      Ab[cur ^ 1][0] = *(const bf16x8*)(Ah + aoff0 + (hs + 1) * 16);
      Ab[cur ^ 1][1] = *(const bf16x8*)(Ah + aoff0 + 32 * SPA + (hs + 1) * 16);
    }
    // 8 MFMA: 4 independent Bh products, then 4 Bl (dep distance 4)
    __builtin_amdgcn_s_setprio(1);
    acc[0][0] = __builtin_amdgcn_mfma_f32_32x32x16_bf16(Ab[cur][0], Bh[cur][0], acc[0][0], 0, 0, 0);
    acc[0][1] = __builtin_amdgcn_mfma_f32_32x32x16_bf16(Ab[cur][0], Bh[cur][1], acc[0][1], 0, 0, 0);
    acc[1][0] = __builtin_amdgcn_mfma_f32_32x32x16_bf16(Ab[cur][1], Bh[cur][0], acc[1][0], 0, 0, 0);
    acc[1][1] = __builtin_amdgcn_mfma_f32_32x32x16_bf16(Ab[cur][1], Bh[cur][1], acc[1][1], 0, 0, 0);
    acc[0][0] = __builtin_amdgcn_mfma_f32_32x32x16_bf16(Ab[cur][0], Bl[cur][0], acc[0][0], 0, 0, 0);
    acc[0][1] = __builtin_amdgcn_mfma_f32_32x32x16_bf16(Ab[cur][0], Bl[cur][1], acc[0][1], 0, 0, 0);
    acc[1][0] = __builtin_amdgcn_mfma_f32_32x32x16_bf16(Ab[cur][1], Bl[cur][0], acc[1][0], 0, 0, 0);
    acc[1][1] = __builtin_amdgcn_mfma_f32_32x32x16_bf16(Ab[cur][1], Bl[cur][1], acc[1][1], 0, 0, 0);
    __builtin_amdgcn_s_setprio(0);
  }

  __syncthreads();   // all waves done reading Ah -> safe to alias its LDS

  // epilogue: v = relu(h2 + b2); p = v*W3 (2 cols/lane presummed);
  // 5-stage shfl over 32 lanes -> per-(row, n-group) partials in LDS
  // (aliasing the dead A tile), final 64-thread reduce + softplus.
  float* PL = (float*)Ah;            // [64][PLS]
  const float bb0 = b2[wave * 64 + r31];
  const float bb1 = b2[wave * 64 + 32 + r31];
  const float w30 = W3[wave * 64 + r31];
  const float w31 = W3[wave * 64 + 32 + r31];
#pragma unroll
  for (int mt = 0; mt < 2; ++mt) {
#pragma unroll
    for (int r = 0; r < 16; ++r) {
      float v0 = acc[mt][0][r] + bb0;
      float v1 = acc[mt][1][r] + bb1;
      v0 = v0 > 0.f ? v0 : 0.f;            // second relu
      v1 = v1 > 0.f ? v1 : 0.f;
      float p = fmaf(v0, w30, v1 * w31);
      p += __shfl_xor(p, 1);
      p += __shfl_xor(p, 2);
      p += __shfl_xor(p, 4);
      p += __shfl_xor(p, 8);
      p += __shfl_xor(p, 16);
      if (r31 == 0) {
        const int row = mt * 32 + (r & 3) + 8 * (r >> 2) + 4 * half;
        PL[row * PLS + wave] = p;
      }
    }
  }
  __syncthreads();
  if (t < 64) {
    float4 q0 = *(const float4*)(PL + t * PLS);
    float4 q1 = *(const float4*)(PL + t * PLS + 4);
    float s = b3[0] + q0.x + q0.y + q0.z + q0.w + q1.x + q1.y + q1.z + q1.w;
    const float sp = s > 0.f ? s + log1pf(expf(-s)) : log1pf(expf(s));
    const int ti = t >> 3, tj = t & 7;
    T1[(i0 + ti) * NPTS + (j0 + tj)] = sp;   // row = i (hy), col = j (hx)
  }
}

// ---------------- parallel lse: one wave per row --------------------------
__global__ __launch_bounds__(512) void rowlse_kernel(
    const float* __restrict__ T1, float* __restrict__ lse) {
  const int r    = blockIdx.x * 8 + (threadIdx.x >> 6);
  const int lane = threadIdx.x & 63;
  const float* row = T1 + r * NPTS;
  float se = 0.f;
#pragma unroll
  for (int q = 0; q < 8; ++q) se += expf(row[lane + q * 64]);
#pragma unroll
  for (int off = 1; off < 64; off <<= 1) se += __shfl_xor(se, off);
  if (lane == 0) lse[r] = logf(se);
}

// ---------------- final: mean(diag) - (mean(lse) - log N) -----------------
__global__ __launch_bounds__(512) void final_kernel(
    const float* __restrict__ T1, const float* __restrict__ lse,
    float* __restrict__ out) {
  __shared__ float s1[8], s2[8];
  const int t = threadIdx.x, lane = t & 63, w = t >> 6;
  float a = T1[t * NPTS + t];   // diag == T0
  float b = lse[t];
#pragma unroll
  for (int off = 1; off < 64; off <<= 1) {
    a += __shfl_xor(a, off);
    b += __shfl_xor(b, off);
  }
  if (lane == 0) { s1[w] = a; s2[w] = b; }
  __syncthreads();
  if (t == 0) {
    float sa = 0.f, sb = 0.f;
#pragma unroll
    for (int i = 0; i < 8; ++i) { sa += s1[i]; sb += s2[i]; }
    out[0] = sa / 512.0f - sb / 512.0f + logf(512.0f);
  }
}

// ---------------------------------------------------------------------------
extern "C" void kernel_launch(void* const* d_in, const int* in_sizes, int n_in,
                              void* d_out, int out_size, void* d_ws, size_t ws_size,
                              hipStream_t stream) {
  const float* x   = (const float*)d_in[0];
  const float* y   = (const float*)d_in[1];
  const float* W1x = (const float*)d_in[2];
  const float* W1y = (const float*)d_in[3];
  const float* b1  = (const float*)d_in[4];
  const float* W2  = (const float*)d_in[5];
  const float* b2  = (const float*)d_in[6];
  const float* W3  = (const float*)d_in[7];
  const float* b3  = (const float*)d_in[8];

  float* ws = (float*)d_ws;
  float* hx = ws;                         // 512*512 f32
  float* hy = ws + 262144;                // 512*512 f32
  float* T1 = ws + 524288;                // 512*512 f32
  __bf16* w2h = (__bf16*)(ws + 786432);   // 512*512 bf16 (fragment-major)
  __bf16* w2l = w2h + 262144;             // 512*512 bf16
  float* lse = ws + 786432 + 131072;      // 512 f32
  float* out = (float*)d_out;

  // dynamic LDS: 64 rows x SPA(520) x 2B = 66560 B (>64 KB default cap)
  static bool configured = false;
  if (!configured) {
    hipFuncSetAttribute(reinterpret_cast<const void*>(pair_kernel),
                        hipFuncAttributeMaxDynamicSharedMemorySize,
                        64 * SPA * 2);
    configured = true;
  }

  hipLaunchKernelGGL(prep_kernel, dim3(1536), dim3(256), 0, stream,
                     x, y, W1x, W1y, b1, W2, hx, hy, w2h, w2l);
  hipLaunchKernelGGL(pair_kernel, dim3(4096), dim3(512), 64 * SPA * 2, stream,
                     hx, hy, w2h, w2l, b2, W3, b3, T1);
  hipLaunchKernelGGL(rowlse_kernel, dim3(64), dim3(512), 0, stream, T1, lse);
  hipLaunchKernelGGL(final_kernel, dim3(1), dim3(512), 0, stream, T1, lse, out);
}